// Round 1
// baseline (1814.279 us; speedup 1.0000x reference)
//
#include <hip/hip_runtime.h>

#define T_STEPS 32
#define BATCH   65536
#define IN_DIM  27
#define H_DIM   10
#define G_DIM   40   // 4*H
#define H2_DIM  5

__device__ __forceinline__ float fast_exp2(float v) {
    return __builtin_amdgcn_exp2f(v);
}
__device__ __forceinline__ float fast_rcp(float v) {
    return __builtin_amdgcn_rcpf(v);
}
// sigmoid(v) = 1/(1+exp(-v)) = rcp(1 + exp2(-v*log2(e)))
__device__ __forceinline__ float fast_sigmoid(float v) {
    return fast_rcp(1.f + fast_exp2(v * -1.4426950408889634f));
}
// tanh(v) = 1 - 2/(exp(2v)+1) = 1 - 2*rcp(exp2(v*2*log2(e)) + 1)
// saturates correctly: v>>0 -> exp2->inf -> rcp->0 -> 1; v<<0 -> exp2->0 -> 1-2 = -1
__device__ __forceinline__ float fast_tanh(float v) {
    return 1.f - 2.f * fast_rcp(1.f + fast_exp2(v * 2.8853900817779268f));
}

__global__ __launch_bounds__(256) void lstm_word_kernel(
    const float* __restrict__ word,   // [T, B, IN]
    const float* __restrict__ W_ih,   // [4H, IN]
    const float* __restrict__ W_hh,   // [4H, H]
    const float* __restrict__ b_ih,   // [4H]
    const float* __restrict__ b_hh,   // [4H]
    const float* __restrict__ W_fc,   // [H2, H]
    const float* __restrict__ b_fc,   // [H2]
    const float* __restrict__ W_out,  // [1, H2]
    const float* __restrict__ b_out,  // [1]
    float* __restrict__ out)          // [B, 1]
{
    const int b = blockIdx.x * blockDim.x + threadIdx.x;

    float h[H_DIM], c[H_DIM];
#pragma unroll
    for (int m = 0; m < H_DIM; ++m) { h[m] = 0.f; c[m] = 0.f; }

    const size_t t_stride = (size_t)BATCH * IN_DIM;
    const size_t row_off  = (size_t)b * IN_DIM;

    // x for t=0
    float x[IN_DIM];
    {
        const float* xp = word + row_off;
#pragma unroll
        for (int k = 0; k < IN_DIM; ++k) x[k] = xp[k];
    }

    for (int t = 0; t < T_STEPS; ++t) {
        // ---- prefetch next timestep's x (clamped on last iter; L1-hit there) ----
        float xn[IN_DIM];
        {
            const int tn = (t + 1 < T_STEPS) ? (t + 1) : t;
            const float* xq = word + (size_t)tn * t_stride + row_off;
#pragma unroll
            for (int k = 0; k < IN_DIM; ++k) xn[k] = xq[k];
        }

        // ---- gates = W_ih @ x + (b_ih + b_hh) + W_hh @ h ----
        float g4[G_DIM];
#pragma unroll
        for (int j = 0; j < G_DIM; ++j) {
            float acc = b_ih[j] + b_hh[j];
            const float* wr = W_ih + j * IN_DIM;
#pragma unroll
            for (int k = 0; k < IN_DIM; ++k) acc = fmaf(wr[k], x[k], acc);
            const float* wh = W_hh + j * H_DIM;
#pragma unroll
            for (int m = 0; m < H_DIM; ++m) acc = fmaf(wh[m], h[m], acc);
            g4[j] = acc;
        }

        // ---- activations + state update (torch gate order i,f,g,o) ----
#pragma unroll
        for (int m = 0; m < H_DIM; ++m) {
            const float iv = fast_sigmoid(g4[m]);
            const float fv = fast_sigmoid(g4[m + H_DIM]);
            const float gv = fast_tanh   (g4[m + 2 * H_DIM]);
            const float ov = fast_sigmoid(g4[m + 3 * H_DIM]);
            const float cn = fmaf(fv, c[m], iv * gv);
            const float hn = ov * fast_tanh(cn);
            h[m] = fmaxf(hn, 0.f);   // reference ReLUs both carries
            c[m] = fmaxf(cn, 0.f);
        }

        // rotate prefetch buffer
#pragma unroll
        for (int k = 0; k < IN_DIM; ++k) x[k] = xn[k];
    }

    // ---- head: relu(h @ W_fc^T + b_fc) -> @ W_out^T + b_out -> sigmoid ----
    float acc = b_out[0];
#pragma unroll
    for (int p = 0; p < H2_DIM; ++p) {
        float y = b_fc[p];
        const float* wf = W_fc + p * H_DIM;
#pragma unroll
        for (int m = 0; m < H_DIM; ++m) y = fmaf(wf[m], h[m], y);
        y = fmaxf(y, 0.f);
        acc = fmaf(W_out[p], y, acc);
    }
    out[b] = fast_sigmoid(acc);
}

extern "C" void kernel_launch(void* const* d_in, const int* in_sizes, int n_in,
                              void* d_out, int out_size, void* d_ws, size_t ws_size,
                              hipStream_t stream) {
    const float* word  = (const float*)d_in[0];
    const float* W_ih  = (const float*)d_in[1];
    const float* W_hh  = (const float*)d_in[2];
    const float* b_ih  = (const float*)d_in[3];
    const float* b_hh  = (const float*)d_in[4];
    const float* W_fc  = (const float*)d_in[5];
    const float* b_fc  = (const float*)d_in[6];
    const float* W_out = (const float*)d_in[7];
    const float* b_out = (const float*)d_in[8];
    float* out = (float*)d_out;

    const int block = 256;
    const int grid  = BATCH / block;  // 65536/256 = 256 blocks -> 1 block/CU
    lstm_word_kernel<<<grid, block, 0, stream>>>(
        word, W_ih, W_hh, b_ih, b_hh, W_fc, b_fc, W_out, b_out, out);
}

// Round 2
// 1746.261 us; speedup vs baseline: 1.0390x; 1.0390x over previous
//
#include <hip/hip_runtime.h>

#define T_STEPS 32
#define BATCH   65536
#define IN_DIM  27
#define H_DIM   10
#define G_DIM   40   // 4*H
#define H2_DIM  5

__device__ __forceinline__ float fast_exp2(float v) {
    return __builtin_amdgcn_exp2f(v);
}
__device__ __forceinline__ float fast_rcp(float v) {
    return __builtin_amdgcn_rcpf(v);
}
// sigmoid(v) = rcp(1 + exp2(-v*log2(e)))
__device__ __forceinline__ float fast_sigmoid(float v) {
    return fast_rcp(1.f + fast_exp2(v * -1.4426950408889634f));
}
// tanh(v) = 1 - 2*rcp(exp2(2v*log2(e)) + 1); saturates correctly at +/-inf
__device__ __forceinline__ float fast_tanh(float v) {
    return 1.f - 2.f * fast_rcp(1.f + fast_exp2(v * 2.8853900817779268f));
}

// __launch_bounds__(256, 1): we are structurally capped at 1 wave/SIMD
// (65536 threads = 1024 waves on 1024 SIMDs), so let the register allocator
// use the full budget — round 1's default budget (VGPR=108 < ~140 live floats)
// forced scratch spills that serialized the whole 32-step loop.
__global__ __launch_bounds__(256, 1) void lstm_word_kernel(
    const float* __restrict__ word,   // [T, B, IN]
    const float* __restrict__ W_ih,   // [4H, IN]
    const float* __restrict__ W_hh,   // [4H, H]
    const float* __restrict__ b_ih,   // [4H]
    const float* __restrict__ b_hh,   // [4H]
    const float* __restrict__ W_fc,   // [H2, H]
    const float* __restrict__ b_fc,   // [H2]
    const float* __restrict__ W_out,  // [1, H2]
    const float* __restrict__ b_out,  // [1]
    float* __restrict__ out)          // [B, 1]
{
    const int b = blockIdx.x * blockDim.x + threadIdx.x;

    // hoist biases out of the t-loop (wave-uniform -> SGPRs/uniform regs)
    float bias[G_DIM];
#pragma unroll
    for (int j = 0; j < G_DIM; ++j) bias[j] = b_ih[j] + b_hh[j];

    float h[H_DIM], c[H_DIM];
#pragma unroll
    for (int m = 0; m < H_DIM; ++m) { h[m] = 0.f; c[m] = 0.f; }

    const size_t t_stride = (size_t)BATCH * IN_DIM;
    const size_t row_off  = (size_t)b * IN_DIM;

    // x for t=0
    float x[IN_DIM];
    {
        const float* xp = word + row_off;
#pragma unroll
        for (int k = 0; k < IN_DIM; ++k) x[k] = xp[k];
    }

    for (int t = 0; t < T_STEPS; ++t) {
        // prefetch next timestep's x early so HBM latency hides under compute
        float xn[IN_DIM];
        {
            const int tn = (t + 1 < T_STEPS) ? (t + 1) : t;
            const float* xq = word + (size_t)tn * t_stride + row_off;
#pragma unroll
            for (int k = 0; k < IN_DIM; ++k) xn[k] = xq[k];
        }

        // per hidden unit m: compute the 4 gate rows (i,f,g,o) and apply the
        // elementwise update immediately. Live accumulator window = 4 floats
        // instead of 40 -> no spill, and the scheduler can prefetch the next
        // unit's (wave-uniform) weight s_loads under the current FMAs.
        float hn[H_DIM];
#pragma unroll
        for (int m = 0; m < H_DIM; ++m) {
            float ai = bias[m];
            float af = bias[m + H_DIM];
            float ag = bias[m + 2 * H_DIM];
            float ao = bias[m + 3 * H_DIM];
            const float* wi = W_ih + m * IN_DIM;
            const float* wf = W_ih + (m + H_DIM) * IN_DIM;
            const float* wg = W_ih + (m + 2 * H_DIM) * IN_DIM;
            const float* wo = W_ih + (m + 3 * H_DIM) * IN_DIM;
#pragma unroll
            for (int k = 0; k < IN_DIM; ++k) {
                const float xv = x[k];
                ai = fmaf(wi[k], xv, ai);
                af = fmaf(wf[k], xv, af);
                ag = fmaf(wg[k], xv, ag);
                ao = fmaf(wo[k], xv, ao);
            }
            const float* hi = W_hh + m * H_DIM;
            const float* hf = W_hh + (m + H_DIM) * H_DIM;
            const float* hg = W_hh + (m + 2 * H_DIM) * H_DIM;
            const float* ho = W_hh + (m + 3 * H_DIM) * H_DIM;
#pragma unroll
            for (int n = 0; n < H_DIM; ++n) {
                const float hv = h[n];
                ai = fmaf(hi[n], hv, ai);
                af = fmaf(hf[n], hv, af);
                ag = fmaf(hg[n], hv, ag);
                ao = fmaf(ho[n], hv, ao);
            }
            const float iv = fast_sigmoid(ai);
            const float fv = fast_sigmoid(af);
            const float gv = fast_tanh(ag);
            const float ov = fast_sigmoid(ao);
            const float cn = fmaf(fv, c[m], iv * gv);
            const float hv = ov * fast_tanh(cn);
            hn[m] = fmaxf(hv, 0.f);   // reference ReLUs both carries
            c[m]  = fmaxf(cn, 0.f);
        }

#pragma unroll
        for (int m = 0; m < H_DIM; ++m) h[m] = hn[m];
#pragma unroll
        for (int k = 0; k < IN_DIM; ++k) x[k] = xn[k];
    }

    // head: relu(h @ W_fc^T + b_fc) -> @ W_out^T + b_out -> sigmoid
    float acc = b_out[0];
#pragma unroll
    for (int p = 0; p < H2_DIM; ++p) {
        float y = b_fc[p];
        const float* wf = W_fc + p * H_DIM;
#pragma unroll
        for (int m = 0; m < H_DIM; ++m) y = fmaf(wf[m], h[m], y);
        y = fmaxf(y, 0.f);
        acc = fmaf(W_out[p], y, acc);
    }
    out[b] = fast_sigmoid(acc);
}

extern "C" void kernel_launch(void* const* d_in, const int* in_sizes, int n_in,
                              void* d_out, int out_size, void* d_ws, size_t ws_size,
                              hipStream_t stream) {
    const float* word  = (const float*)d_in[0];
    const float* W_ih  = (const float*)d_in[1];
    const float* W_hh  = (const float*)d_in[2];
    const float* b_ih  = (const float*)d_in[3];
    const float* b_hh  = (const float*)d_in[4];
    const float* W_fc  = (const float*)d_in[5];
    const float* b_fc  = (const float*)d_in[6];
    const float* W_out = (const float*)d_in[7];
    const float* b_out = (const float*)d_in[8];
    float* out = (float*)d_out;

    const int block = 256;
    const int grid  = BATCH / block;  // 256 blocks -> 1 block/CU
    lstm_word_kernel<<<grid, block, 0, stream>>>(
        word, W_ih, W_hh, b_ih, b_hh, W_fc, b_fc, W_out, b_out, out);
}

// Round 3
// 281.092 us; speedup vs baseline: 6.4544x; 6.2124x over previous
//
#include <hip/hip_runtime.h>

#define T_STEPS 32
#define BATCH   65536
#define IN_DIM  27
#define INP     28          // W_ih rows padded to 28 floats (16B-aligned, x[27]=0)
#define H_DIM   10
#define HP      12          // W_hh rows padded to 12 floats (16B-aligned, h[10..11]=0)
#define G_DIM   40          // 4*H
#define H2_DIM  5

__device__ __forceinline__ float fast_exp2(float v) { return __builtin_amdgcn_exp2f(v); }
__device__ __forceinline__ float fast_rcp(float v)  { return __builtin_amdgcn_rcpf(v); }
// sigmoid(v) = rcp(1 + exp2(-v*log2(e)))
__device__ __forceinline__ float fast_sigmoid(float v) {
    return fast_rcp(1.f + fast_exp2(v * -1.4426950408889634f));
}
// tanh(v) = 1 - 2*rcp(exp2(2v*log2(e)) + 1); saturates correctly at +/-inf
__device__ __forceinline__ float fast_tanh(float v) {
    return 1.f - 2.f * fast_rcp(1.f + fast_exp2(v * 2.8853900817779268f));
}

// ---------------------------------------------------------------------------
// Pass 1: gates_x[t][j][b] = x[t,b,:] @ W_ih[j,:] + b_ih[j] + b_hh[j]
// Output layout [T][4H][B] so pass 2 reads are lane-coalesced.
// 8192 blocks -> 4 blocks/CU resident (LDS 32KB) -> 4 waves/SIMD of TLP:
// weight-load latency is hidden by other waves, unlike the fused kernel.
// ---------------------------------------------------------------------------
__global__ __launch_bounds__(256) void input_proj_kernel(
    const float* __restrict__ word,   // [T, B, IN]
    const float* __restrict__ W_ih,   // [4H, IN]
    const float* __restrict__ b_ih,   // [4H]
    const float* __restrict__ b_hh,   // [4H]
    float* __restrict__ gx)           // [T, 4H, B]
{
    __shared__ float s_x[256 * IN_DIM];   // 27648 B, this block's x chunk
    __shared__ float s_w[G_DIM * INP];    //  4480 B, padded W_ih
    __shared__ float s_b[G_DIM];

    const int tid = threadIdx.x;
    const int t   = blockIdx.y;
    const int b0  = blockIdx.x * 256;

    // stage x chunk: 256 rows x 27 floats, contiguous in global -> coalesced
    const float* src = word + ((size_t)t * BATCH + b0) * IN_DIM;
#pragma unroll
    for (int i = 0; i < IN_DIM; ++i) s_x[tid + 256 * i] = src[tid + 256 * i];

    // stage W_ih with rows padded to 28 (pad = 0)
    for (int idx = tid; idx < G_DIM * INP; idx += 256) {
        const int j = idx / INP, k = idx - j * INP;
        s_w[idx] = (k < IN_DIM) ? W_ih[j * IN_DIM + k] : 0.f;
    }
    if (tid < G_DIM) s_b[tid] = b_ih[tid] + b_hh[tid];
    __syncthreads();

    // per-lane x into registers (stride-27 LDS reads: 27 coprime 32 -> no conflicts)
    float xr[INP];
#pragma unroll
    for (int k = 0; k < IN_DIM; ++k) xr[k] = s_x[tid * IN_DIM + k];
    xr[IN_DIM] = 0.f;

    float* dst = gx + (size_t)t * G_DIM * BATCH + (size_t)(b0 + tid);
#pragma unroll
    for (int j = 0; j < G_DIM; j += 2) {
        float a0 = s_b[j], a1 = s_b[j + 1];
        const float* w0 = s_w + j * INP;
        const float* w1 = w0 + INP;
#pragma unroll
        for (int k = 0; k < INP; k += 4) {
            const float4 q0 = *(const float4*)(w0 + k);  // ds_read_b128 broadcast
            const float4 q1 = *(const float4*)(w1 + k);
            a0 = fmaf(q0.x, xr[k    ], a0);
            a0 = fmaf(q0.y, xr[k + 1], a0);
            a0 = fmaf(q0.z, xr[k + 2], a0);
            a0 = fmaf(q0.w, xr[k + 3], a0);
            a1 = fmaf(q1.x, xr[k    ], a1);
            a1 = fmaf(q1.y, xr[k + 1], a1);
            a1 = fmaf(q1.z, xr[k + 2], a1);
            a1 = fmaf(q1.w, xr[k + 3], a1);
        }
        dst[(size_t)j * BATCH]       = a0;   // coalesced: lanes = consecutive b
        dst[(size_t)(j + 1) * BATCH] = a1;
    }
}

// ---------------------------------------------------------------------------
// Pass 2: 32-step recurrence + head. Per step only W_hh (400 FMAs, LDS
// broadcast) + 40 coalesced gx loads prefetched one step ahead.
// ---------------------------------------------------------------------------
__global__ __launch_bounds__(256, 1) void recurrence_kernel(
    const float* __restrict__ gx,     // [T, 4H, B]
    const float* __restrict__ W_hh,   // [4H, H]
    const float* __restrict__ W_fc,   // [H2, H]
    const float* __restrict__ b_fc,   // [H2]
    const float* __restrict__ W_out,  // [1, H2]
    const float* __restrict__ b_out,  // [1]
    float* __restrict__ out)          // [B]
{
    __shared__ float s_whh[G_DIM * HP];    // padded W_hh rows
    __shared__ float s_fc[H2_DIM * HP];    // padded W_fc rows
    __shared__ float s_bfc[H2_DIM];
    __shared__ float s_wo[H2_DIM];
    __shared__ float s_bo;

    const int tid = threadIdx.x;
    for (int idx = tid; idx < G_DIM * HP; idx += 256) {
        const int j = idx / HP, k = idx - j * HP;
        s_whh[idx] = (k < H_DIM) ? W_hh[j * H_DIM + k] : 0.f;
    }
    if (tid < H2_DIM * HP) {
        const int j = tid / HP, k = tid - j * HP;
        s_fc[tid] = (k < H_DIM) ? W_fc[j * H_DIM + k] : 0.f;
    }
    if (tid < H2_DIM) { s_bfc[tid] = b_fc[tid]; s_wo[tid] = W_out[tid]; }
    if (tid == 0) s_bo = b_out[0];
    __syncthreads();

    const int b = blockIdx.x * 256 + tid;

    float h[HP], c[H_DIM];
#pragma unroll
    for (int m = 0; m < HP; ++m) h[m] = 0.f;
#pragma unroll
    for (int m = 0; m < H_DIM; ++m) c[m] = 0.f;

    const float* gbase = gx + (size_t)b;

    // t=0 gates (x-part)
    float cur[G_DIM];
#pragma unroll
    for (int j = 0; j < G_DIM; ++j) cur[j] = gbase[(size_t)j * BATCH];

    for (int t = 0; t < T_STEPS; ++t) {
        // prefetch next step's x-gates early; latency hides under this step's
        // compute (coalesced: lane = consecutive b)
        float nxt[G_DIM];
        {
            const int tn = (t + 1 < T_STEPS) ? (t + 1) : t;
            const float* gp = gbase + (size_t)tn * G_DIM * BATCH;
#pragma unroll
            for (int j = 0; j < G_DIM; ++j) nxt[j] = gp[(size_t)j * BATCH];
        }

        float hn[H_DIM];
#pragma unroll
        for (int m = 0; m < H_DIM; ++m) {
            float ai = cur[m];
            float af = cur[m + H_DIM];
            float ag = cur[m + 2 * H_DIM];
            float ao = cur[m + 3 * H_DIM];
            const float* wi = s_whh + m * HP;
            const float* wf = s_whh + (m + H_DIM) * HP;
            const float* wg = s_whh + (m + 2 * H_DIM) * HP;
            const float* wo = s_whh + (m + 3 * H_DIM) * HP;
#pragma unroll
            for (int k = 0; k < HP; k += 4) {
                const float4 qi = *(const float4*)(wi + k);
                const float4 qf = *(const float4*)(wf + k);
                const float4 qg = *(const float4*)(wg + k);
                const float4 qo = *(const float4*)(wo + k);
                ai = fmaf(qi.x, h[k], fmaf(qi.y, h[k+1], fmaf(qi.z, h[k+2], fmaf(qi.w, h[k+3], ai))));
                af = fmaf(qf.x, h[k], fmaf(qf.y, h[k+1], fmaf(qf.z, h[k+2], fmaf(qf.w, h[k+3], af))));
                ag = fmaf(qg.x, h[k], fmaf(qg.y, h[k+1], fmaf(qg.z, h[k+2], fmaf(qg.w, h[k+3], ag))));
                ao = fmaf(qo.x, h[k], fmaf(qo.y, h[k+1], fmaf(qo.z, h[k+2], fmaf(qo.w, h[k+3], ao))));
            }
            const float iv = fast_sigmoid(ai);
            const float fv = fast_sigmoid(af);
            const float gv = fast_tanh(ag);
            const float ov = fast_sigmoid(ao);
            const float cn = fmaf(fv, c[m], iv * gv);
            const float hv = ov * fast_tanh(cn);
            hn[m] = fmaxf(hv, 0.f);   // reference ReLUs both carries
            c[m]  = fmaxf(cn, 0.f);
        }

#pragma unroll
        for (int m = 0; m < H_DIM; ++m) h[m] = hn[m];
#pragma unroll
        for (int j = 0; j < G_DIM; ++j) cur[j] = nxt[j];
    }

    // head: relu(h @ W_fc^T + b_fc) -> @ W_out^T + b_out -> sigmoid
    float acc = s_bo;
#pragma unroll
    for (int p = 0; p < H2_DIM; ++p) {
        float y = s_bfc[p];
        const float* wf = s_fc + p * HP;
#pragma unroll
        for (int m = 0; m < H_DIM; ++m) y = fmaf(wf[m], h[m], y);
        y = fmaxf(y, 0.f);
        acc = fmaf(s_wo[p], y, acc);
    }
    out[b] = fast_sigmoid(acc);
}

// ---------------------------------------------------------------------------
// Fallback (round-2 fused kernel) if workspace is too small for gates_x.
// ---------------------------------------------------------------------------
__global__ __launch_bounds__(256, 1) void lstm_word_fused_kernel(
    const float* __restrict__ word, const float* __restrict__ W_ih,
    const float* __restrict__ W_hh, const float* __restrict__ b_ih,
    const float* __restrict__ b_hh, const float* __restrict__ W_fc,
    const float* __restrict__ b_fc, const float* __restrict__ W_out,
    const float* __restrict__ b_out, float* __restrict__ out)
{
    const int b = blockIdx.x * blockDim.x + threadIdx.x;
    float bias[G_DIM];
#pragma unroll
    for (int j = 0; j < G_DIM; ++j) bias[j] = b_ih[j] + b_hh[j];
    float h[H_DIM], c[H_DIM];
#pragma unroll
    for (int m = 0; m < H_DIM; ++m) { h[m] = 0.f; c[m] = 0.f; }
    const size_t t_stride = (size_t)BATCH * IN_DIM;
    const size_t row_off  = (size_t)b * IN_DIM;
    float x[IN_DIM];
    {
        const float* xp = word + row_off;
#pragma unroll
        for (int k = 0; k < IN_DIM; ++k) x[k] = xp[k];
    }
    for (int t = 0; t < T_STEPS; ++t) {
        float xn[IN_DIM];
        {
            const int tn = (t + 1 < T_STEPS) ? (t + 1) : t;
            const float* xq = word + (size_t)tn * t_stride + row_off;
#pragma unroll
            for (int k = 0; k < IN_DIM; ++k) xn[k] = xq[k];
        }
        float hn[H_DIM];
#pragma unroll
        for (int m = 0; m < H_DIM; ++m) {
            float ai = bias[m], af = bias[m + H_DIM], ag = bias[m + 2*H_DIM], ao = bias[m + 3*H_DIM];
            const float* wi = W_ih + m * IN_DIM;
            const float* wf = W_ih + (m + H_DIM) * IN_DIM;
            const float* wg = W_ih + (m + 2*H_DIM) * IN_DIM;
            const float* wo = W_ih + (m + 3*H_DIM) * IN_DIM;
#pragma unroll
            for (int k = 0; k < IN_DIM; ++k) {
                const float xv = x[k];
                ai = fmaf(wi[k], xv, ai); af = fmaf(wf[k], xv, af);
                ag = fmaf(wg[k], xv, ag); ao = fmaf(wo[k], xv, ao);
            }
            const float* hi = W_hh + m * H_DIM;
            const float* hf = W_hh + (m + H_DIM) * H_DIM;
            const float* hg = W_hh + (m + 2*H_DIM) * H_DIM;
            const float* ho = W_hh + (m + 3*H_DIM) * H_DIM;
#pragma unroll
            for (int n = 0; n < H_DIM; ++n) {
                const float hv = h[n];
                ai = fmaf(hi[n], hv, ai); af = fmaf(hf[n], hv, af);
                ag = fmaf(hg[n], hv, ag); ao = fmaf(ho[n], hv, ao);
            }
            const float iv = fast_sigmoid(ai), fv = fast_sigmoid(af);
            const float gv = fast_tanh(ag),    ov = fast_sigmoid(ao);
            const float cn = fmaf(fv, c[m], iv * gv);
            const float hv = ov * fast_tanh(cn);
            hn[m] = fmaxf(hv, 0.f);
            c[m]  = fmaxf(cn, 0.f);
        }
#pragma unroll
        for (int m = 0; m < H_DIM; ++m) h[m] = hn[m];
#pragma unroll
        for (int k = 0; k < IN_DIM; ++k) x[k] = xn[k];
    }
    float acc = b_out[0];
#pragma unroll
    for (int p = 0; p < H2_DIM; ++p) {
        float y = b_fc[p];
        const float* wf = W_fc + p * H_DIM;
#pragma unroll
        for (int m = 0; m < H_DIM; ++m) y = fmaf(wf[m], h[m], y);
        y = fmaxf(y, 0.f);
        acc = fmaf(W_out[p], y, acc);
    }
    out[b] = fast_sigmoid(acc);
}

extern "C" void kernel_launch(void* const* d_in, const int* in_sizes, int n_in,
                              void* d_out, int out_size, void* d_ws, size_t ws_size,
                              hipStream_t stream) {
    const float* word  = (const float*)d_in[0];
    const float* W_ih  = (const float*)d_in[1];
    const float* W_hh  = (const float*)d_in[2];
    const float* b_ih  = (const float*)d_in[3];
    const float* b_hh  = (const float*)d_in[4];
    const float* W_fc  = (const float*)d_in[5];
    const float* b_fc  = (const float*)d_in[6];
    const float* W_out = (const float*)d_in[7];
    const float* b_out = (const float*)d_in[8];
    float* out = (float*)d_out;

    const size_t need = (size_t)T_STEPS * G_DIM * BATCH * sizeof(float); // 335.5 MB
    if (ws_size >= need) {
        float* gxbuf = (float*)d_ws;
        dim3 grid1(BATCH / 256, T_STEPS);
        input_proj_kernel<<<grid1, 256, 0, stream>>>(word, W_ih, b_ih, b_hh, gxbuf);
        recurrence_kernel<<<BATCH / 256, 256, 0, stream>>>(
            gxbuf, W_hh, W_fc, b_fc, W_out, b_out, out);
    } else {
        lstm_word_fused_kernel<<<BATCH / 256, 256, 0, stream>>>(
            word, W_ih, W_hh, b_ih, b_hh, W_fc, b_fc, W_out, b_out, out);
    }
}